// Round 3
// baseline (4699.556 us; speedup 1.0000x reference)
//
#include <hip/hip_runtime.h>
#include <hip/hip_bf16.h>
#include <stdint.h>

#define DD 32
#define KH 96   // 3*D

// ws layout:
//  hdr (uint32):
//   [0] idx_mode (0=int64,1=int32)  [1] sel_mode (0=i64,1=i32,2=bytes)
//   [2] fmode (0=bf16,1=fp32)       [3] min_key (encoded, atomicMin ALL sp)
//   [4] max_key (legacy, unsel)     [5] cnt_unsel
//   [6] S bits                      [7] mfma_ok (self-test)
//   [8] M bits (softmax max, plain float bits)
//  ws+256   : float Wf[3072]        (f32 W, [96][32] row-major)
//  ws+12544 : float bf[32]
//  ws+12672 : float vf[32]          (g - sg)
//  ws+12800 : u16 Wfrag[3072]       (A-fragments: [kk 0..5][lane 0..63][e 0..7])
//  ws+20480 : float2 pairs[2048]    (per-block online (max,sum))
//  ws+36864 : float sp[E]           (if ws_size permits; else sp lives in d_out)

typedef __attribute__((ext_vector_type(16))) float vf16;    // SGPR payload (slow path)
typedef __attribute__((ext_vector_type(8)))  short bf16x8;  // MFMA A/B frag
typedef __attribute__((ext_vector_type(16))) float f32x16;  // MFMA C/D frag

__device__ __forceinline__ uint32_t fkey(float f) {
    uint32_t b = __float_as_uint(f);
    return (b & 0x80000000u) ? ~b : (b | 0x80000000u);
}
__device__ __forceinline__ float funkey(uint32_t k) {
    uint32_t b = (k & 0x80000000u) ? (k & 0x7FFFFFFFu) : ~k;
    return __uint_as_float(b);
}
__device__ __forceinline__ float bflo(uint32_t w) { return __uint_as_float(w << 16); }
__device__ __forceinline__ float bfhi(uint32_t w) { return __uint_as_float(w & 0xFFFF0000u); }
__device__ __forceinline__ uint16_t f2bf(float v) {
    uint32_t u = __float_as_uint(v);
    uint32_t r = (u + 0x7FFFu + ((u >> 16) & 1u)) >> 16;
    return (uint16_t)r;
}

// wave-uniform scalar load of 32 floats into SGPRs (slow path only)
__device__ __forceinline__ void wload(const float* p, vf16& a, vf16& b) {
    asm volatile("s_load_dwordx16 %0, %2, 0x0\n\t"
                 "s_load_dwordx16 %1, %2, 0x40\n\t"
                 "s_waitcnt lgkmcnt(0)"
                 : "=&s"(a), "=&s"(b)
                 : "s"(p));
}

// direct HBM->LDS, 16B per lane. LDS dest = wave-uniform base + lane*16 (HW rule).
#define GLL16(gp, lp) __builtin_amdgcn_global_load_lds( \
    (const __attribute__((address_space(1))) unsigned int*)(gp), \
    (__attribute__((address_space(3))) unsigned int*)(lp), 16, 0, 0)

// online-softmax pair combine: (m,s) <- combine((m,s),(om,os)); guards all -inf.
__device__ __forceinline__ void comb(float& m, float& s, float om, float os) {
    float M2 = fmaxf(m, om);
    if (M2 == -__builtin_inff()) { m = M2; s = 0.f; return; }
    s = s * __expf((m - M2) * 2.f) + os * __expf((om - M2) * 2.f);
    m = M2;
}

__global__ void k_init(const void* W, const void* bias, const void* g, const void* sg,
                       const void* ei, const void* sel,
                       uint32_t* hdr, float* Wf, float* bf, float* vf,
                       uint16_t* wfrag, int E, int N) {
    int t = threadIdx.x;
    __shared__ int sh_i32, sh_gt1, sh_odd, sh_f32, sh_mok;
    if (t == 0) { sh_i32 = 0; sh_gt1 = 0; sh_odd = 0; sh_f32 = 0; sh_mok = 1; }
    __syncthreads();

    const uint16_t* wb = (const uint16_t*)W;
    for (int i = t; i < KH * DD; i += 256) {
        float x = bflo((uint32_t)wb[i]);
        if (!(fabsf(x) < 1e4f)) sh_f32 = 1;
    }
    const long long* ell = (const long long*)ei;
    int ns = 2048 < E ? 2048 : E;
    for (int i = t; i < ns; i += 256) {
        long long v = ell[i];
        if (v < 0 || v >= (long long)N) sh_i32 = 1;
    }
    const uint32_t* sw = (const uint32_t*)sel;
    int ns2 = 2048 < E / 4 ? 2048 : E / 4;
    for (int i = t; i < ns2; i += 256) {
        uint32_t v = sw[i];
        if (v > 1u) sh_gt1 = 1;
        if (v != 0u && (i & 1)) sh_odd = 1;
    }
    __syncthreads();
    int fmode = sh_f32;

    for (int i = t; i < KH * DD; i += 256)
        Wf[i] = fmode ? ((const float*)W)[i] : bflo((uint32_t)wb[i]);
    for (int i = t; i < DD; i += 256) {
        bf[i] = fmode ? ((const float*)bias)[i] : bflo((uint32_t)((const uint16_t*)bias)[i]);
        float gv = fmode ? ((const float*)g)[i]  : bflo((uint32_t)((const uint16_t*)g)[i]);
        float sv = fmode ? ((const float*)sg)[i] : bflo((uint32_t)((const uint16_t*)sg)[i]);
        vf[i] = gv - sv;
    }
    __syncthreads();

    // pack A-fragments: Wfrag[kk][lane][e] = bf16(W^T[lane&31][kk*16 + 8*(lane>>5)+e])
    for (int i = t; i < 3072; i += 256) {
        int kk = i >> 9;
        int ln = (i >> 3) & 63;
        int e2 = i & 7;
        int k  = kk * 16 + 8 * (ln >> 5) + e2;
        int j  = ln & 31;
        wfrag[i] = f2bf(Wf[k * DD + j]);
    }

    // MFMA layout self-test on exact small-int data (wave 0).
    // k-mapping errors cancel (same permutation on A and B); this validates the
    // i/j/C mappings that actually matter. On mismatch -> scalar fallback.
    if (t < 64) {
        int hf = t >> 5, cl = t & 31;
        bf16x8 ta, tb;
        #pragma unroll
        for (int e2 = 0; e2 < 8; ++e2) {
            int k = 8 * hf + e2;
            ta[e2] = (short)f2bf((float)(((2 * cl + k) & 7) + 1));  // A[i=cl][k]
            tb[e2] = (short)f2bf((float)(((k + 3 * cl) & 7) + 1));  // B[k][j=cl]
        }
        f32x16 cc = {};
        cc = __builtin_amdgcn_mfma_f32_32x32x16_bf16(ta, tb, cc, 0, 0, 0);
        bool ok = true;
        #pragma unroll
        for (int r = 0; r < 16; ++r) {
            int i2 = (r & 3) + 8 * (r >> 2) + 4 * hf;  // C row
            int j2 = cl;                               // C col
            float ev = 0.f;
            for (int k = 0; k < 16; ++k)
                ev += (float)((((2 * i2 + k) & 7) + 1) * (((k + 3 * j2) & 7) + 1));
            if (cc[r] != ev) ok = false;
        }
        if (!__all(ok) && t == 0) sh_mok = 0;
    }
    __syncthreads();

    if (t == 0) {
        hdr[0] = (uint32_t)sh_i32;
        hdr[1] = sh_gt1 ? 2u : (sh_odd ? 1u : 0u);
        hdr[2] = (uint32_t)fmode;
        hdr[3] = 0xFFFFFFFFu;
        hdr[4] = 0u;
        hdr[5] = 0u;
        hdr[6] = 0u;
        hdr[7] = (uint32_t)sh_mok;
        hdr[8] = 0u;
    }
}

__device__ __forceinline__ void loadrow(const char* __restrict__ p, int fmode, float* h) {
    if (fmode) {
        const float4* q = (const float4*)p;
        #pragma unroll
        for (int t = 0; t < 8; ++t) {
            float4 u = q[t];
            h[t * 4 + 0] = u.x; h[t * 4 + 1] = u.y; h[t * 4 + 2] = u.z; h[t * 4 + 3] = u.w;
        }
    } else {
        const uint4* q = (const uint4*)p;
        #pragma unroll
        for (int t = 0; t < 4; ++t) {
            uint4 u = q[t];
            h[t * 8 + 0] = bflo(u.x); h[t * 8 + 1] = bfhi(u.x);
            h[t * 8 + 2] = bflo(u.y); h[t * 8 + 3] = bfhi(u.y);
            h[t * 8 + 4] = bflo(u.z); h[t * 8 + 5] = bfhi(u.z);
            h[t * 8 + 6] = bflo(u.w); h[t * 8 + 7] = bfhi(u.w);
        }
    }
}

__device__ __forceinline__ bool fetch_sel(const char* sel, int mode, int e) {
    if (mode == 2) return ((const uint8_t*)sel)[e] != 0;
    if (mode == 1) return ((const int*)sel)[e] != 0;
    return ((const long long*)sel)[e] != 0;
}

__device__ __forceinline__ void sp_store(float* __restrict__ ws_sp, void* __restrict__ out,
                                         int use_ws, int fmode, int e, float v) {
    if (use_ws) ws_sp[e] = v;
    else if (fmode) ((float*)out)[e] = v;
    else ((uint16_t*)out)[e] = f2bf(v);
}
__device__ __forceinline__ float sp_load(const float* __restrict__ ws_sp, const void* __restrict__ out,
                                         int use_ws, int fmode, int e) {
    if (use_ws) return ws_sp[e];
    if (fmode) return ((const float*)out)[e];
    return bflo((uint32_t)((const uint16_t*)out)[e]);
}

__device__ __forceinline__ void finalize_block(
    float mn, float mx, uint32_t c, float mM, float mS,
    uint32_t* __restrict__ hdr, float2* __restrict__ pairs, int use_ws,
    float* s_mn, float* s_mx, uint32_t* s_c, float* s_m, float* s_s) {
    #pragma unroll
    for (int o = 32; o >= 1; o >>= 1) {
        mn = fminf(mn, __shfl_xor(mn, o));
        mx = fmaxf(mx, __shfl_xor(mx, o));
        c += __shfl_xor(c, o);
        float om = __shfl_xor(mM, o), os = __shfl_xor(mS, o);
        comb(mM, mS, om, os);
    }
    int wid = threadIdx.x >> 6, lane = threadIdx.x & 63;
    if (lane == 0) { s_mn[wid] = mn; s_mx[wid] = mx; s_c[wid] = c; s_m[wid] = mM; s_s[wid] = mS; }
    __syncthreads();
    if (threadIdx.x == 0) {
        for (int w = 1; w < 4; ++w) {
            mn = fminf(mn, s_mn[w]); mx = fmaxf(mx, s_mx[w]); c += s_c[w];
            comb(mM, mS, s_m[w], s_s[w]);
        }
        atomicMin(&hdr[3], fkey(mn));
        atomicMax(&hdr[4], fkey(mx));
        if (c) atomicAdd(&hdr[5], c);
        if (use_ws) pairs[blockIdx.x] = make_float2(mM, mS);
    }
}

__global__ __launch_bounds__(256, 3) void k_pass1(
    const char* __restrict__ node, const char* __restrict__ edgep,
    const char* __restrict__ ei, const char* __restrict__ sel,
    uint32_t* __restrict__ hdr, const float* __restrict__ Wf,
    const float* __restrict__ bf, const float* __restrict__ vf,
    const uint16_t* __restrict__ wfrag, float2* __restrict__ pairs,
    float* __restrict__ ws_sp, void* __restrict__ out,
    int use_ws, int E, int N) {
    const int idx_mode = (int)hdr[0];
    const int sel_mode = (int)hdr[1];
    const int fmode    = (int)hdr[2];
    const int mok      = (int)hdr[7];

    __shared__ char lds_raw[49152];            // 4 waves x 12KB staging
    __shared__ float s_mn[4], s_mx[4], s_m[4], s_s[4];
    __shared__ uint32_t s_c[4];

    float mnA = __builtin_inff();
    float mxA = -__builtin_inff();
    float mM  = -__builtin_inff();
    float mS  = 0.f;
    uint32_t cA = 0;

    if (fmode == 0 && mok && use_ws) {
        // ---------------- MFMA fast path (bf16) ----------------
        int lane = threadIdx.x & 63;
        int wid  = threadIdx.x >> 6;
        int hf   = lane >> 5;       // k-half
        int cl   = lane & 31;       // A row / B col / C col
        int ldsb = wid * 12288;

        bf16x8 wf[6];
        #pragma unroll
        for (int kk = 0; kk < 6; ++kk)
            wf[kk] = *(const bf16x8*)(wfrag + kk * 512 + lane * 8);
        float vv[16], bb[16];
        #pragma unroll
        for (int r = 0; r < 16; ++r) {
            int j = (r & 3) + 8 * (r >> 2) + 4 * hf;   // C row = output dim
            vv[r] = vf[j];
            bb[r] = bf[j];
        }

        int nchunk = (E + 63) >> 6;
        int cstride = gridDim.x * 4;
        for (int chunk = blockIdx.x * 4 + wid; chunk < nchunk; chunk += cstride) {
            int e0 = chunk << 6;
            int e  = e0 + lane;
            bool valid = e < E;
            int ec = valid ? e : E - 1;

            long long siv, div_;
            if (idx_mode) { siv = ((const int*)ei)[ec]; div_ = ((const int*)ei)[E + ec]; }
            else          { siv = ((const long long*)ei)[ec]; div_ = ((const long long*)ei)[(size_t)E + ec]; }
            int s0 = (int)siv; s0 = s0 < 0 ? 0 : (s0 >= N ? N - 1 : s0);
            int d0 = (int)div_; d0 = d0 < 0 ? 0 : (d0 >= N ? N - 1 : d0);

            const char* ps = node  + (size_t)s0 * 64;
            const char* pd = node  + (size_t)d0 * 64;
            const char* pe = edgep + (size_t)ec * 64;

            bool selv = valid ? fetch_sel(sel, sel_mode, ec) : true;

            // prev iter's ds_reads must have returned before LDS overwrite
            asm volatile("s_waitcnt lgkmcnt(0)" ::: "memory");
            #pragma unroll
            for (int sg = 0; sg < 4; ++sg) GLL16(ps + sg * 16, &lds_raw[ldsb + sg * 1024]);
            #pragma unroll
            for (int sg = 0; sg < 4; ++sg) GLL16(pd + sg * 16, &lds_raw[ldsb + (4 + sg) * 1024]);
            #pragma unroll
            for (int sg = 0; sg < 4; ++sg) GLL16(pe + sg * 16, &lds_raw[ldsb + (8 + sg) * 1024]);
            asm volatile("s_waitcnt vmcnt(0)" ::: "memory");

            f32x16 a0 = {}, a1 = {};
            #pragma unroll
            for (int kk = 0; kk < 6; ++kk) {
                int cbase = ldsb + (kk * 2 + hf) * 1024 + cl * 16;
                bf16x8 b0 = *(const bf16x8*)&lds_raw[cbase];
                bf16x8 b1 = *(const bf16x8*)&lds_raw[cbase + 512];
                a0 = __builtin_amdgcn_mfma_f32_32x32x16_bf16(wf[kk], b0, a0, 0, 0, 0);
                a1 = __builtin_amdgcn_mfma_f32_32x32x16_bf16(wf[kk], b1, a1, 0, 0, 0);
            }

            float p0 = 0.f, p1 = 0.f;
            #pragma unroll
            for (int r = 0; r < 16; ++r) {
                float x0 = a0[r] + bb[r];
                float y0 = x0 > 0.f ? x0 : (__expf(x0) - 1.f);
                p0 = fmaf(y0, vv[r], p0);
                float x1 = a1[r] + bb[r];
                float y1 = x1 > 0.f ? x1 : (__expf(x1) - 1.f);
                p1 = fmaf(y1, vv[r], p1);
            }
            p0 += __shfl_xor(p0, 32);
            p1 += __shfl_xor(p1, 32);
            float spv = (lane < 32) ? p0 : p1;   // lane l owns edge e0+l

            if (valid) {
                sp_store(ws_sp, out, use_ws, fmode, e, spv);
                mnA = fminf(mnA, spv);
                if (!selv) {
                    cA++;
                    mxA = fmaxf(mxA, spv);
                    comb(mM, mS, spv, 1.f);
                }
            }
        }
    } else {
        // ---------------- scalar fallback (proven round-0 structure) ----------------
        const int stride = gridDim.x * 256;
        for (int e = blockIdx.x * 256 + threadIdx.x; e < E; e += stride) {
            long long siv, div_;
            if (idx_mode) { siv = ((const int*)ei)[e]; div_ = ((const int*)ei)[E + e]; }
            else          { siv = ((const long long*)ei)[e]; div_ = ((const long long*)ei)[(size_t)E + e]; }
            int s0 = (int)siv; s0 = s0 < 0 ? 0 : (s0 >= N ? N - 1 : s0);
            int d0 = (int)div_; d0 = d0 < 0 ? 0 : (d0 >= N ? N - 1 : d0);

            size_t rb = fmode ? 128 : 64;
            const char* p0 = node  + (size_t)s0 * rb;
            const char* p1 = node  + (size_t)d0 * rb;
            const char* p2 = edgep + (size_t)e * rb;

            float acc[DD];
            {
                vf16 b0, b1;
                wload(bf, b0, b1);
                #pragma unroll
                for (int j = 0; j < 16; ++j) { acc[j] = b0[j]; acc[16 + j] = b1[j]; }
            }
            float hh[32], hn[32];
            loadrow(p0, fmode, hh);
            #pragma unroll 1
            for (int r = 0; r < 3; ++r) {
                if (r < 2) loadrow(r == 0 ? p1 : p2, fmode, hn);
                const float* wp = Wf + r * 32 * DD;
                #pragma unroll
                for (int k = 0; k < 32; ++k) {
                    vf16 w0, w1;
                    wload(wp + k * DD, w0, w1);
                    float hk = hh[k];
                    #pragma unroll
                    for (int j = 0; j < 16; ++j) {
                        acc[j]      = fmaf(hk, w0[j], acc[j]);
                        acc[16 + j] = fmaf(hk, w1[j], acc[16 + j]);
                    }
                }
                if (r < 2) {
                    #pragma unroll
                    for (int k = 0; k < 32; ++k) hh[k] = hn[k];
                }
            }
            float spv = 0.f;
            {
                vf16 v0, v1;
                wload(vf, v0, v1);
                #pragma unroll
                for (int j = 0; j < 16; ++j) {
                    float a = acc[j];
                    float act = a > 0.f ? a : (__expf(a) - 1.f);
                    spv = fmaf(act, v0[j], spv);
                    float a2 = acc[16 + j];
                    float act2 = a2 > 0.f ? a2 : (__expf(a2) - 1.f);
                    spv = fmaf(act2, v1[j], spv);
                }
            }
            sp_store(ws_sp, out, use_ws, fmode, e, spv);
            bool selv = fetch_sel(sel, sel_mode, e);
            mnA = fminf(mnA, spv);
            if (!selv) {
                cA++;
                mxA = fmaxf(mxA, spv);
                comb(mM, mS, spv, 1.f);
            }
        }
    }

    finalize_block(mnA, mxA, cA, mM, mS, hdr, pairs, use_ws,
                   s_mn, s_mx, s_c, s_m, s_s);
}

// 1-block reduce of per-block (max,sum) pairs -> global M, S (use_ws path).
__global__ void k_reduce(uint32_t* __restrict__ hdr, const float2* __restrict__ pairs,
                         int nb, int E) {
    float m = -__builtin_inff(), s = 0.f;
    for (int i = threadIdx.x; i < nb; i += 256) {
        float2 p = pairs[i];
        comb(m, s, p.x, p.y);
    }
    #pragma unroll
    for (int o = 32; o >= 1; o >>= 1) {
        float om = __shfl_xor(m, o), os = __shfl_xor(s, o);
        comb(m, s, om, os);
    }
    __shared__ float sm[4], ss[4];
    int wid = threadIdx.x >> 6, lane = threadIdx.x & 63;
    if (lane == 0) { sm[wid] = m; ss[wid] = s; }
    __syncthreads();
    if (threadIdx.x == 0) {
        for (int w = 1; w < 4; ++w) comb(m, s, sm[w], ss[w]);
        uint32_t cnt = hdr[5];
        float mn = funkey(hdr[3]);
        float M = cnt ? m : mn;
        float S = (cnt ? s : 0.f) + (float)(E - (int)cnt) * __expf((mn - M) * 2.f);
        hdr[8] = __float_as_uint(M);
        hdr[6] = __float_as_uint(S);
    }
}

// legacy pass2 (only when !use_ws): full sweep computing S; also publishes M.
__global__ __launch_bounds__(256) void k_pass2(
    const char* __restrict__ sel, uint32_t* __restrict__ hdr,
    const float* __restrict__ ws_sp, const void* __restrict__ out,
    int use_ws, int E) {
    int sel_mode = (int)hdr[1], fmode = (int)hdr[2];
    float mn = funkey(hdr[3]);
    uint32_t cnt = hdr[5];
    float M = cnt ? funkey(hdr[4]) : mn;
    if (blockIdx.x == 0 && threadIdx.x == 0) hdr[8] = __float_as_uint(M);

    float p = 0.f;
    const int stride = gridDim.x * 256;
    for (int e = blockIdx.x * 256 + threadIdx.x; e < E; e += stride) {
        float sp = sp_load(ws_sp, out, use_ws, fmode, e);
        bool selv = fetch_sel(sel, sel_mode, e);
        float masked = selv ? mn : sp;
        p += __expf((masked - M) * 2.0f);
    }
    #pragma unroll
    for (int o = 32; o >= 1; o >>= 1) p += __shfl_xor(p, o);
    __shared__ float sps[4];
    int wid = threadIdx.x >> 6, lane = threadIdx.x & 63;
    if (lane == 0) sps[wid] = p;
    __syncthreads();
    if (threadIdx.x == 0) {
        p += sps[1] + sps[2] + sps[3];
        atomicAdd((float*)&hdr[6], p);
    }
}

__global__ __launch_bounds__(256) void k_pass3(
    const char* __restrict__ sel, const uint32_t* __restrict__ hdr,
    const float* __restrict__ ws_sp, void* __restrict__ out,
    int use_ws, int E) {
    int sel_mode = (int)hdr[1], fmode = (int)hdr[2];
    float mn = funkey(hdr[3]);
    float M = __uint_as_float(hdr[8]);
    float S = __uint_as_float(hdr[6]);
    const int stride = gridDim.x * 256;
    for (int e = blockIdx.x * 256 + threadIdx.x; e < E; e += stride) {
        float sp = sp_load(ws_sp, out, use_ws, fmode, e);
        bool selv = fetch_sel(sel, sel_mode, e);
        float masked = selv ? mn : sp;
        float r = __expf((masked - M) * 2.0f) / S;
        if (fmode) ((float*)out)[e] = r;
        else       ((uint16_t*)out)[e] = f2bf(r);
    }
}

extern "C" void kernel_launch(void* const* d_in, const int* in_sizes, int n_in,
                              void* d_out, int out_size, void* d_ws, size_t ws_size,
                              hipStream_t stream) {
    int N = in_sizes[0] / DD;
    int E = in_sizes[1] / DD;
    const void* node = d_in[0];
    const void* edge = d_in[1];
    const void* g    = d_in[2];
    const void* sg   = d_in[3];
    const void* W    = d_in[4];
    const void* bias = d_in[5];
    const void* ei   = d_in[6];
    const void* sel  = d_in[7];

    uint8_t* ws = (uint8_t*)d_ws;
    uint32_t* hdr = (uint32_t*)ws;
    float* Wf       = (float*)(ws + 256);
    float* bf       = (float*)(ws + 12544);
    float* vf       = (float*)(ws + 12672);
    uint16_t* wfrag = (uint16_t*)(ws + 12800);
    float2* pairs   = (float2*)(ws + 20480);
    float* sp_arr   = (float*)(ws + 36864);
    int use_ws = (ws_size >= (size_t)36864 + (size_t)E * sizeof(float)) ? 1 : 0;

    int full = (E + 255) / 256;
    int grid1  = full < 2048 ? full : 2048;
    int grid23 = full < 1024 ? full : 1024;

    k_init<<<1, 256, 0, stream>>>(W, bias, g, sg, ei, sel, hdr, Wf, bf, vf, wfrag, E, N);
    k_pass1<<<grid1, 256, 0, stream>>>((const char*)node, (const char*)edge, (const char*)ei,
                                       (const char*)sel, hdr, Wf, bf, vf, wfrag, pairs,
                                       sp_arr, d_out, use_ws, E, N);
    if (use_ws)
        k_reduce<<<1, 256, 0, stream>>>(hdr, pairs, grid1, E);
    else
        k_pass2<<<grid23, 256, 0, stream>>>((const char*)sel, hdr, sp_arr, d_out, use_ws, E);
    k_pass3<<<grid23, 256, 0, stream>>>((const char*)sel, hdr, sp_arr, d_out, use_ws, E);
}